// Round 2
// baseline (229.382 us; speedup 1.0000x reference)
//
#include <hip/hip_runtime.h>
#include <hip/hip_bf16.h>
#include <stdint.h>

// Problem constants (from reference)
#define Bq 32
#define Sq 512
#define Hq 1024
#define Tq 100
#define Fq 512
#define Lq 5
#define EPSq 1e-5f

typedef float fx4 __attribute__((ext_vector_type(4)));
typedef __bf16 bfx8 __attribute__((ext_vector_type(8)));
typedef unsigned short u16x8 __attribute__((ext_vector_type(8)));

static __device__ __forceinline__ unsigned short f2bf(float f) {
  unsigned int u = __builtin_bit_cast(unsigned int, f);
  return (unsigned short)((u + 0x7fffu + ((u >> 16) & 1u)) >> 16);  // RNE (finite inputs)
}
static __device__ __forceinline__ float bf2f(unsigned short s) {
  return __builtin_bit_cast(float, ((unsigned int)s) << 16);
}

// ---------------------------------------------------------------- convert seq f32 -> bf16
__global__ void k_convert_seq(const float* __restrict__ in, unsigned short* __restrict__ out) {
  int i = blockIdx.x * blockDim.x + threadIdx.x;   // 8 elems per thread, grid exact
  const float4* p = (const float4*)in + (size_t)i * 2;
  float4 a = p[0], b = p[1];
  u16x8 o;
  o[0] = f2bf(a.x); o[1] = f2bf(a.y); o[2] = f2bf(a.z); o[3] = f2bf(a.w);
  o[4] = f2bf(b.x); o[5] = f2bf(b.y); o[6] = f2bf(b.z); o[7] = f2bf(b.w);
  *((u16x8*)out + i) = o;
}

// ---------------------------------------------------------------- W1 [L][H][H] f32 -> W1T [L][e][h] bf16
__global__ void k_transpose_w1(const float* __restrict__ w1, unsigned short* __restrict__ w1t) {
  __shared__ float t[32][33];
  int blk = blockIdx.x;
  int l = blk >> 10; int rem = blk & 1023; int tr = rem >> 5; int tc = rem & 31;
  const float* src = w1 + (size_t)l * Hq * Hq;
  unsigned short* dst = w1t + (size_t)l * Hq * Hq;
  int tx = threadIdx.x, ty = threadIdx.y;  // 32 x 8
#pragma unroll
  for (int p = 0; p < 4; p++)
    t[ty + 8 * p][tx] = src[(size_t)(tr * 32 + ty + 8 * p) * Hq + tc * 32 + tx];
  __syncthreads();
#pragma unroll
  for (int p = 0; p < 4; p++)
    dst[(size_t)(tc * 32 + ty + 8 * p) * Hq + tr * 32 + tx] = f2bf(t[tx][ty + 8 * p]);
}

// ---------------------------------------------------------------- GEMM1: H1 = seq @ W1[lang] + b1, bf16 out
// Per-batch M=512,N=1024,K=1024. 128x128 tile, 4 waves (2x2 of 64x64), BK=32.
// LDS rows padded 32->40 shorts (+16B) to spread the 64B-stride frag reads across banks.
__global__ __launch_bounds__(256) void k_gemm1(const unsigned short* __restrict__ seqbf,
                                               const unsigned short* __restrict__ w1t,
                                               const float* __restrict__ b1,
                                               const int* __restrict__ lid,
                                               unsigned short* __restrict__ h1bf) {
  __shared__ short sA[128 * 40];
  __shared__ short sB[128 * 40];
  int bid = blockIdx.x;
  int b = bid >> 5; int t = bid & 31; int tm = t >> 3; int tn = t & 7;
  int lang = lid[b];
  const unsigned short* Ab = seqbf + (size_t)b * Sq * Hq + (size_t)tm * 128 * Hq;
  const unsigned short* Bb = w1t + (size_t)lang * Hq * Hq + (size_t)tn * 128 * Hq;

  int tid = threadIdx.x;
  int lane = tid & 63; int wid = tid >> 6;
  int wr = wid >> 1, wc = wid & 1;
  int fr = lane & 15;              // A row / B col within 16
  int fk = (lane >> 4) * 8;        // k offset within 32

  int c0 = tid, c1 = tid + 256;    // 16B chunks: row = c>>2, kblock = c&3
  const unsigned short* gA0 = Ab + (size_t)(c0 >> 2) * Hq + (c0 & 3) * 8;
  const unsigned short* gA1 = Ab + (size_t)(c1 >> 2) * Hq + (c1 & 3) * 8;
  const unsigned short* gB0 = Bb + (size_t)(c0 >> 2) * Hq + (c0 & 3) * 8;
  const unsigned short* gB1 = Bb + (size_t)(c1 >> 2) * Hq + (c1 & 3) * 8;
  short* lA0 = &sA[(c0 >> 2) * 40 + (c0 & 3) * 8];
  short* lA1 = &sA[(c1 >> 2) * 40 + (c1 & 3) * 8];
  short* lB0 = &sB[(c0 >> 2) * 40 + (c0 & 3) * 8];
  short* lB1 = &sB[(c1 >> 2) * 40 + (c1 & 3) * 8];

  fx4 acc[4][4];
#pragma unroll
  for (int m = 0; m < 4; m++)
#pragma unroll
    for (int n = 0; n < 4; n++) acc[m][n] = (fx4){0.f, 0.f, 0.f, 0.f};

  // prologue: load tile 0
  u16x8 va0 = *(const u16x8*)gA0;
  u16x8 va1 = *(const u16x8*)gA1;
  u16x8 vb0 = *(const u16x8*)gB0;
  u16x8 vb1 = *(const u16x8*)gB1;

  for (int kt = 0; kt < 32; kt++) {
    __syncthreads();               // previous compute done before overwrite
    *(u16x8*)lA0 = va0; *(u16x8*)lA1 = va1;
    *(u16x8*)lB0 = vb0; *(u16x8*)lB1 = vb1;
    __syncthreads();
    if (kt < 31) {                 // issue next-tile loads early; hide under MFMA
      int ko = (kt + 1) * 32;
      va0 = *(const u16x8*)(gA0 + ko);
      va1 = *(const u16x8*)(gA1 + ko);
      vb0 = *(const u16x8*)(gB0 + ko);
      vb1 = *(const u16x8*)(gB1 + ko);
    }
    bfx8 af[4], bfr[4];
#pragma unroll
    for (int m = 0; m < 4; m++)
      af[m] = *(const bfx8*)&sA[(wr * 64 + m * 16 + fr) * 40 + fk];
#pragma unroll
    for (int n = 0; n < 4; n++)
      bfr[n] = *(const bfx8*)&sB[(wc * 64 + n * 16 + fr) * 40 + fk];
#pragma unroll
    for (int m = 0; m < 4; m++)
#pragma unroll
      for (int n = 0; n < 4; n++)
        acc[m][n] = __builtin_amdgcn_mfma_f32_16x16x32_bf16(af[m], bfr[n], acc[m][n], 0, 0, 0);
  }

  // epilogue: + b1, convert, store bf16. C/D: row=(lane>>4)*4+r, col=lane&15 (m89-verified)
  unsigned short* Cb = h1bf + (size_t)b * Sq * Hq;
  float bv[4];
#pragma unroll
  for (int n = 0; n < 4; n++)
    bv[n] = b1[lang * Hq + tn * 128 + wc * 64 + n * 16 + fr];
  int r0 = (lane >> 4) * 4;
#pragma unroll
  for (int m = 0; m < 4; m++) {
#pragma unroll
    for (int n = 0; n < 4; n++) {
      int col = tn * 128 + wc * 64 + n * 16 + fr;
#pragma unroll
      for (int r = 0; r < 4; r++) {
        int row = tm * 128 + wr * 64 + m * 16 + r0 + r;
        Cb[(size_t)row * Hq + col] = f2bf(acc[m][n][r] + bv[n]);
      }
    }
  }
}

// ---------------------------------------------------------------- LN + relu + masked pool partials
// grid = B*8 (chunks of 64 rows); 4 waves x 16 rows; one wave owns a full 1024-elem row
__global__ __launch_bounds__(256) void k_ln_pool(const unsigned short* __restrict__ h1bf,
                                                 const float* __restrict__ g1,
                                                 const float* __restrict__ be1,
                                                 const float* __restrict__ mask,
                                                 const int* __restrict__ lid,
                                                 float* __restrict__ partial) {
  __shared__ float sacc[4][1024];
  int blk = blockIdx.x; int b = blk >> 3; int ch = blk & 7;
  int tid = threadIdx.x; int lane = tid & 63; int w = tid >> 6;
  int lang = lid[b];
  int e0 = lane * 8;
  int e1 = 512 + lane * 8;

  const float4* gp = (const float4*)(g1 + (size_t)lang * Hq);
  const float4* bp = (const float4*)(be1 + (size_t)lang * Hq);
  float4 ga0 = gp[lane * 2], ga1 = gp[lane * 2 + 1];
  float4 gb0 = gp[128 + lane * 2], gb1 = gp[129 + lane * 2];
  float4 ba0 = bp[lane * 2], ba1 = bp[lane * 2 + 1];
  float4 bb0 = bp[128 + lane * 2], bb1 = bp[129 + lane * 2];
  float gA[8] = {ga0.x, ga0.y, ga0.z, ga0.w, ga1.x, ga1.y, ga1.z, ga1.w};
  float gB[8] = {gb0.x, gb0.y, gb0.z, gb0.w, gb1.x, gb1.y, gb1.z, gb1.w};
  float bA[8] = {ba0.x, ba0.y, ba0.z, ba0.w, ba1.x, ba1.y, ba1.z, ba1.w};
  float bB[8] = {bb0.x, bb0.y, bb0.z, bb0.w, bb1.x, bb1.y, bb1.z, bb1.w};

  float acc0[8] = {0, 0, 0, 0, 0, 0, 0, 0}, acc1[8] = {0, 0, 0, 0, 0, 0, 0, 0};

  for (int i = 0; i < 16; i++) {
    int s = ch * 64 + w * 16 + i;
    const unsigned short* rowp = h1bf + ((size_t)b * Sq + s) * Hq;
    u16x8 va = *(const u16x8*)(rowp + e0);
    u16x8 vb = *(const u16x8*)(rowp + e1);
    float xa[8], xb[8];
    float sum = 0.f, sq = 0.f;
#pragma unroll
    for (int j = 0; j < 8; j++) {
      xa[j] = bf2f(va[j]); sum += xa[j]; sq += xa[j] * xa[j];
      xb[j] = bf2f(vb[j]); sum += xb[j]; sq += xb[j] * xb[j];
    }
#pragma unroll
    for (int off = 1; off < 64; off <<= 1) {
      sum += __shfl_xor(sum, off, 64);
      sq += __shfl_xor(sq, off, 64);
    }
    float mu = sum * (1.f / Hq);
    float var = sq * (1.f / Hq) - mu * mu;
    float rstd = rsqrtf(var + EPSq);
    float mw = mask[b * Sq + s];
#pragma unroll
    for (int j = 0; j < 8; j++) {
      float y0 = fmaxf((xa[j] - mu) * rstd * gA[j] + bA[j], 0.f);
      float y1 = fmaxf((xb[j] - mu) * rstd * gB[j] + bB[j], 0.f);
      acc0[j] += mw * y0;
      acc1[j] += mw * y1;
    }
  }
#pragma unroll
  for (int j = 0; j < 8; j++) {
    sacc[w][e0 + j] = acc0[j];
    sacc[w][e1 + j] = acc1[j];
  }
  __syncthreads();
  int e = tid * 4;
#pragma unroll
  for (int j = 0; j < 4; j++)
    partial[(size_t)blk * Hq + e + j] =
        sacc[0][e + j] + sacc[1][e + j] + sacc[2][e + j] + sacc[3][e + j];
}

// ---------------------------------------------------------------- reduce partials, / masksum
__global__ void k_reduce_pool(const float* __restrict__ partial, const float* __restrict__ mask,
                              float* __restrict__ pooled) {
  __shared__ float wsum[4];
  int b = blockIdx.x; int tid = threadIdx.x;  // 256
  float mv = mask[b * Sq + tid] + mask[b * Sq + 256 + tid];
#pragma unroll
  for (int off = 1; off < 64; off <<= 1) mv += __shfl_xor(mv, off, 64);
  if ((tid & 63) == 0) wsum[tid >> 6] = mv;
  __syncthreads();
  float inv = 1.0f / (wsum[0] + wsum[1] + wsum[2] + wsum[3]);
  int e = tid * 4;
#pragma unroll
  for (int j = 0; j < 4; j++) {
    float s = 0.f;
#pragma unroll
    for (int c = 0; c < 8; c++) s += partial[((size_t)b * 8 + c) * Hq + e + j];
    pooled[b * Hq + e + j] = s * inv;
  }
}

// ---------------------------------------------------------------- pooled @ W2[lang] + b2  (f32)
__global__ __launch_bounds__(128) void k_gemm2(const float* __restrict__ pooled,
                                               const float* __restrict__ w2,
                                               const float* __restrict__ b2,
                                               const int* __restrict__ lid,
                                               float* __restrict__ pooledf) {
  __shared__ float pl[1024];
  int blk = blockIdx.x; int b = blk >> 3; int ch = blk & 7;
  int tid = threadIdx.x; int lang = lid[b];
#pragma unroll
  for (int j = 0; j < 8; j++) pl[tid + 128 * j] = pooled[b * Hq + tid + 128 * j];
  __syncthreads();
  int col = ch * 128 + tid;
  const float* W = w2 + (size_t)lang * Hq * Hq + col;
  float acc = 0.f;
#pragma unroll 8
  for (int e = 0; e < 1024; e++) acc += pl[e] * W[(size_t)e * Hq];
  pooledf[b * Hq + col] = acc + b2[lang * Hq + col];
}

// ---------------------------------------------------------------- concat + @Wf + bf + LN + relu -> f32 out
__global__ __launch_bounds__(512) void k_final(const float* __restrict__ pooledf,
                                               const float* __restrict__ lda,
                                               const float* __restrict__ wf,
                                               const float* __restrict__ bff,
                                               const float* __restrict__ gf,
                                               const float* __restrict__ betaf,
                                               float* __restrict__ out) {
  __shared__ float comb[Hq + Tq];
  __shared__ float rsum[8], rsq[8];
  int b = blockIdx.x; int tid = threadIdx.x;  // 512
  comb[tid] = pooledf[b * Hq + tid];
  comb[512 + tid] = pooledf[b * Hq + 512 + tid];
  if (tid < Tq) comb[1024 + tid] = lda[b * Tq + tid];
  __syncthreads();
  float acc = bff[tid];
#pragma unroll 4
  for (int k = 0; k < Hq + Tq; k++) acc += comb[k] * wf[(size_t)k * Fq + tid];
  float s = acc, q = acc * acc;
#pragma unroll
  for (int off = 1; off < 64; off <<= 1) {
    s += __shfl_xor(s, off, 64);
    q += __shfl_xor(q, off, 64);
  }
  int w = tid >> 6, lane = tid & 63;
  if (lane == 0) { rsum[w] = s; rsq[w] = q; }
  __syncthreads();
  float S = 0.f, Q = 0.f;
#pragma unroll
  for (int i = 0; i < 8; i++) { S += rsum[i]; Q += rsq[i]; }
  float mu = S * (1.f / Fq);
  float var = Q * (1.f / Fq) - mu * mu;
  float y = (acc - mu) * rsqrtf(var + EPSq) * gf[tid] + betaf[tid];
  y = fmaxf(y, 0.f);
  out[b * Fq + tid] = y;   // FLOAT32 output (threshold evidence: no bf16 floor applied)
}

// ----------------------------------------------------------------
extern "C" void kernel_launch(void* const* d_in, const int* in_sizes, int n_in,
                              void* d_out, int out_size, void* d_ws, size_t ws_size,
                              hipStream_t stream) {
  const float* seq = (const float*)d_in[0];
  const float* mask = (const float*)d_in[1];
  const int* lid = (const int*)d_in[2];
  const float* lda = (const float*)d_in[3];
  const float* W1 = (const float*)d_in[4];
  const float* b1 = (const float*)d_in[5];
  const float* g1 = (const float*)d_in[6];
  const float* be1 = (const float*)d_in[7];
  const float* W2 = (const float*)d_in[8];
  const float* b2 = (const float*)d_in[9];
  const float* Wf = (const float*)d_in[10];
  const float* bff = (const float*)d_in[11];
  const float* gf = (const float*)d_in[12];
  const float* betaf = (const float*)d_in[13];
  float* out = (float*)d_out;  // f32 output

  // workspace layout (~78.9 MB total)
  char* ws = (char*)d_ws;
  unsigned short* seqbf = (unsigned short*)(ws);                  // 33,554,432 B
  unsigned short* w1t = (unsigned short*)(ws + 33554432);         // 10,485,760 B
  unsigned short* h1bf = (unsigned short*)(ws + 44040192);        // 33,554,432 B
  float* partial = (float*)(ws + 77594624);                       //  1,048,576 B
  float* pooled = (float*)(ws + 78643200);                        //    131,072 B
  float* pooledf = (float*)(ws + 78774272);                       //    131,072 B

  k_convert_seq<<<8192, 256, 0, stream>>>(seq, seqbf);
  k_transpose_w1<<<5120, dim3(32, 8), 0, stream>>>(W1, w1t);
  k_gemm1<<<1024, 256, 0, stream>>>(seqbf, w1t, b1, lid, h1bf);
  k_ln_pool<<<256, 256, 0, stream>>>(h1bf, g1, be1, mask, lid, partial);
  k_reduce_pool<<<32, 256, 0, stream>>>(partial, mask, pooled);
  k_gemm2<<<256, 128, 0, stream>>>(pooled, W2, b2, lid, pooledf);
  k_final<<<32, 512, 0, stream>>>(pooledf, lda, Wf, bff, gf, betaf, out);
}

// Round 3
// 123.940 us; speedup vs baseline: 1.8507x; 1.8507x over previous
//
#include <hip/hip_runtime.h>
#include <hip/hip_bf16.h>
#include <stdint.h>

// Problem constants (from reference)
#define Bq 32
#define Sq 512
#define Hq 1024
#define Tq 100
#define Fq 512
#define Lq 5
#define EPSq 1e-5f

typedef float fx4 __attribute__((ext_vector_type(4)));
typedef __bf16 bfx8 __attribute__((ext_vector_type(8)));
typedef unsigned short u16x8 __attribute__((ext_vector_type(8)));

static __device__ __forceinline__ unsigned short f2bf(float f) {
  unsigned int u = __builtin_bit_cast(unsigned int, f);
  return (unsigned short)((u + 0x7fffu + ((u >> 16) & 1u)) >> 16);  // RNE (finite inputs)
}
static __device__ __forceinline__ float bf2f(unsigned short s) {
  return __builtin_bit_cast(float, ((unsigned int)s) << 16);
}

// ---------------------------------------------------------------- convert seq f32 -> bf16
__global__ void k_convert_seq(const float* __restrict__ in, unsigned short* __restrict__ out) {
  int i = blockIdx.x * blockDim.x + threadIdx.x;   // 8 elems per thread, grid exact
  const float4* p = (const float4*)in + (size_t)i * 2;
  float4 a = p[0], b = p[1];
  u16x8 o;
  o[0] = f2bf(a.x); o[1] = f2bf(a.y); o[2] = f2bf(a.z); o[3] = f2bf(a.w);
  o[4] = f2bf(b.x); o[5] = f2bf(b.y); o[6] = f2bf(b.z); o[7] = f2bf(b.w);
  *((u16x8*)out + i) = o;
}

// ---------------------------------------------------------------- W1 [L][H][H] f32 -> W1T [L][e][h] bf16
__global__ void k_transpose_w1(const float* __restrict__ w1, unsigned short* __restrict__ w1t) {
  __shared__ float t[32][33];
  int blk = blockIdx.x;
  int l = blk >> 10; int rem = blk & 1023; int tr = rem >> 5; int tc = rem & 31;
  const float* src = w1 + (size_t)l * Hq * Hq;
  unsigned short* dst = w1t + (size_t)l * Hq * Hq;
  int tx = threadIdx.x, ty = threadIdx.y;  // 32 x 8
#pragma unroll
  for (int p = 0; p < 4; p++)
    t[ty + 8 * p][tx] = src[(size_t)(tr * 32 + ty + 8 * p) * Hq + tc * 32 + tx];
  __syncthreads();
#pragma unroll
  for (int p = 0; p < 4; p++)
    dst[(size_t)(tc * 32 + ty + 8 * p) * Hq + tr * 32 + tx] = f2bf(t[tx][ty + 8 * p]);
}

// ---------------------------------------------------------------- GEMM1: H1 = seq @ W1[lang] + b1, bf16 out
__global__ __launch_bounds__(256) void k_gemm1(const unsigned short* __restrict__ seqbf,
                                               const unsigned short* __restrict__ w1t,
                                               const float* __restrict__ b1,
                                               const int* __restrict__ lid,
                                               unsigned short* __restrict__ h1bf) {
  __shared__ short sA[128 * 40];
  __shared__ short sB[128 * 40];
  int bid = blockIdx.x;
  int b = bid >> 5; int t = bid & 31; int tm = t >> 3; int tn = t & 7;
  int lang = lid[b];
  const unsigned short* Ab = seqbf + (size_t)b * Sq * Hq + (size_t)tm * 128 * Hq;
  const unsigned short* Bb = w1t + (size_t)lang * Hq * Hq + (size_t)tn * 128 * Hq;

  int tid = threadIdx.x;
  int lane = tid & 63; int wid = tid >> 6;
  int wr = wid >> 1, wc = wid & 1;
  int fr = lane & 15;              // A row / B col within 16
  int fk = (lane >> 4) * 8;        // k offset within 32

  int c0 = tid, c1 = tid + 256;    // 16B chunks: row = c>>2, kblock = c&3
  const unsigned short* gA0 = Ab + (size_t)(c0 >> 2) * Hq + (c0 & 3) * 8;
  const unsigned short* gA1 = Ab + (size_t)(c1 >> 2) * Hq + (c1 & 3) * 8;
  const unsigned short* gB0 = Bb + (size_t)(c0 >> 2) * Hq + (c0 & 3) * 8;
  const unsigned short* gB1 = Bb + (size_t)(c1 >> 2) * Hq + (c1 & 3) * 8;
  short* lA0 = &sA[(c0 >> 2) * 40 + (c0 & 3) * 8];
  short* lA1 = &sA[(c1 >> 2) * 40 + (c1 & 3) * 8];
  short* lB0 = &sB[(c0 >> 2) * 40 + (c0 & 3) * 8];
  short* lB1 = &sB[(c1 >> 2) * 40 + (c1 & 3) * 8];

  fx4 acc[4][4];
#pragma unroll
  for (int m = 0; m < 4; m++)
#pragma unroll
    for (int n = 0; n < 4; n++) acc[m][n] = (fx4){0.f, 0.f, 0.f, 0.f};

  u16x8 va0 = *(const u16x8*)gA0;
  u16x8 va1 = *(const u16x8*)gA1;
  u16x8 vb0 = *(const u16x8*)gB0;
  u16x8 vb1 = *(const u16x8*)gB1;

  for (int kt = 0; kt < 32; kt++) {
    __syncthreads();
    *(u16x8*)lA0 = va0; *(u16x8*)lA1 = va1;
    *(u16x8*)lB0 = vb0; *(u16x8*)lB1 = vb1;
    __syncthreads();
    if (kt < 31) {
      int ko = (kt + 1) * 32;
      va0 = *(const u16x8*)(gA0 + ko);
      va1 = *(const u16x8*)(gA1 + ko);
      vb0 = *(const u16x8*)(gB0 + ko);
      vb1 = *(const u16x8*)(gB1 + ko);
    }
    bfx8 af[4], bfr[4];
#pragma unroll
    for (int m = 0; m < 4; m++)
      af[m] = *(const bfx8*)&sA[(wr * 64 + m * 16 + fr) * 40 + fk];
#pragma unroll
    for (int n = 0; n < 4; n++)
      bfr[n] = *(const bfx8*)&sB[(wc * 64 + n * 16 + fr) * 40 + fk];
#pragma unroll
    for (int m = 0; m < 4; m++)
#pragma unroll
      for (int n = 0; n < 4; n++)
        acc[m][n] = __builtin_amdgcn_mfma_f32_16x16x32_bf16(af[m], bfr[n], acc[m][n], 0, 0, 0);
  }

  unsigned short* Cb = h1bf + (size_t)b * Sq * Hq;
  float bv[4];
#pragma unroll
  for (int n = 0; n < 4; n++)
    bv[n] = b1[lang * Hq + tn * 128 + wc * 64 + n * 16 + fr];
  int r0 = (lane >> 4) * 4;
#pragma unroll
  for (int m = 0; m < 4; m++) {
#pragma unroll
    for (int n = 0; n < 4; n++) {
      int col = tn * 128 + wc * 64 + n * 16 + fr;
#pragma unroll
      for (int r = 0; r < 4; r++) {
        int row = tm * 128 + wr * 64 + m * 16 + r0 + r;
        Cb[(size_t)row * Hq + col] = f2bf(acc[m][n][r] + bv[n]);
      }
    }
  }
}

// ---------------------------------------------------------------- LN + relu + masked pool partials
__global__ __launch_bounds__(256) void k_ln_pool(const unsigned short* __restrict__ h1bf,
                                                 const float* __restrict__ g1,
                                                 const float* __restrict__ be1,
                                                 const float* __restrict__ mask,
                                                 const int* __restrict__ lid,
                                                 float* __restrict__ partial) {
  __shared__ float sacc[4][1024];
  int blk = blockIdx.x; int b = blk >> 3; int ch = blk & 7;
  int tid = threadIdx.x; int lane = tid & 63; int w = tid >> 6;
  int lang = lid[b];
  int e0 = lane * 8;
  int e1 = 512 + lane * 8;

  const float4* gp = (const float4*)(g1 + (size_t)lang * Hq);
  const float4* bp = (const float4*)(be1 + (size_t)lang * Hq);
  float4 ga0 = gp[lane * 2], ga1 = gp[lane * 2 + 1];
  float4 gb0 = gp[128 + lane * 2], gb1 = gp[129 + lane * 2];
  float4 ba0 = bp[lane * 2], ba1 = bp[lane * 2 + 1];
  float4 bb0 = bp[128 + lane * 2], bb1 = bp[129 + lane * 2];
  float gA[8] = {ga0.x, ga0.y, ga0.z, ga0.w, ga1.x, ga1.y, ga1.z, ga1.w};
  float gB[8] = {gb0.x, gb0.y, gb0.z, gb0.w, gb1.x, gb1.y, gb1.z, gb1.w};
  float bA[8] = {ba0.x, ba0.y, ba0.z, ba0.w, ba1.x, ba1.y, ba1.z, ba1.w};
  float bB[8] = {bb0.x, bb0.y, bb0.z, bb0.w, bb1.x, bb1.y, bb1.z, bb1.w};

  float acc0[8] = {0, 0, 0, 0, 0, 0, 0, 0}, acc1[8] = {0, 0, 0, 0, 0, 0, 0, 0};

  for (int i = 0; i < 16; i++) {
    int s = ch * 64 + w * 16 + i;
    const unsigned short* rowp = h1bf + ((size_t)b * Sq + s) * Hq;
    u16x8 va = *(const u16x8*)(rowp + e0);
    u16x8 vb = *(const u16x8*)(rowp + e1);
    float xa[8], xb[8];
    float sum = 0.f, sq = 0.f;
#pragma unroll
    for (int j = 0; j < 8; j++) {
      xa[j] = bf2f(va[j]); sum += xa[j]; sq += xa[j] * xa[j];
      xb[j] = bf2f(vb[j]); sum += xb[j]; sq += xb[j] * xb[j];
    }
#pragma unroll
    for (int off = 1; off < 64; off <<= 1) {
      sum += __shfl_xor(sum, off, 64);
      sq += __shfl_xor(sq, off, 64);
    }
    float mu = sum * (1.f / Hq);
    float var = sq * (1.f / Hq) - mu * mu;
    float rstd = rsqrtf(var + EPSq);
    float mw = mask[b * Sq + s];
#pragma unroll
    for (int j = 0; j < 8; j++) {
      float y0 = fmaxf((xa[j] - mu) * rstd * gA[j] + bA[j], 0.f);
      float y1 = fmaxf((xb[j] - mu) * rstd * gB[j] + bB[j], 0.f);
      acc0[j] += mw * y0;
      acc1[j] += mw * y1;
    }
  }
#pragma unroll
  for (int j = 0; j < 8; j++) {
    sacc[w][e0 + j] = acc0[j];
    sacc[w][e1 + j] = acc1[j];
  }
  __syncthreads();
  int e = tid * 4;
#pragma unroll
  for (int j = 0; j < 4; j++)
    partial[(size_t)blk * Hq + e + j] =
        sacc[0][e + j] + sacc[1][e + j] + sacc[2][e + j] + sacc[3][e + j];
}

// ---------------------------------------------------------------- reduce partials, / masksum
__global__ void k_reduce_pool(const float* __restrict__ partial, const float* __restrict__ mask,
                              float* __restrict__ pooled) {
  __shared__ float wsum[4];
  int b = blockIdx.x; int tid = threadIdx.x;  // 256
  float mv = mask[b * Sq + tid] + mask[b * Sq + 256 + tid];
#pragma unroll
  for (int off = 1; off < 64; off <<= 1) mv += __shfl_xor(mv, off, 64);
  if ((tid & 63) == 0) wsum[tid >> 6] = mv;
  __syncthreads();
  float inv = 1.0f / (wsum[0] + wsum[1] + wsum[2] + wsum[3]);
  int e = tid * 4;
#pragma unroll
  for (int j = 0; j < 4; j++) {
    float s = 0.f;
#pragma unroll
    for (int c = 0; c < 8; c++) s += partial[((size_t)b * 8 + c) * Hq + e + j];
    pooled[b * Hq + e + j] = s * inv;
  }
}

// ---------------------------------------------------------------- pooled @ W2[lang] split-K partials
// grid = 32b x 2colchunk x 4kslice = 256 blocks, 256 thr, float2 cols, 8-deep load batching
__global__ __launch_bounds__(256) void k_gemm2p(const float* __restrict__ pooled,
                                                const float* __restrict__ w2,
                                                const int* __restrict__ lid,
                                                float* __restrict__ g2part) {
  __shared__ float pl[256];
  int blk = blockIdx.x;
  int b = blk >> 3; int ch = (blk >> 2) & 1; int ks = blk & 3;
  int tid = threadIdx.x;
  int lang = lid[b];
  pl[tid] = pooled[b * Hq + ks * 256 + tid];
  __syncthreads();
  int col = ch * 512 + tid * 2;
  const float* W = w2 + (size_t)lang * Hq * Hq + (size_t)ks * 256 * Hq + col;
  float a0 = 0.f, a1 = 0.f;
  for (int e0 = 0; e0 < 256; e0 += 8) {
    float2 w[8];
#pragma unroll
    for (int j = 0; j < 8; j++) w[j] = *(const float2*)(W + (size_t)(e0 + j) * Hq);
#pragma unroll
    for (int j = 0; j < 8; j++) { float c = pl[e0 + j]; a0 += c * w[j].x; a1 += c * w[j].y; }
  }
  float2* dst = (float2*)(g2part + ((size_t)(b * 4 + ks) * Hq) + col);
  *dst = make_float2(a0, a1);
}

// ---------------------------------------------------------------- sum k-slices + b2 -> pooledf
__global__ __launch_bounds__(256) void k_gemm2red(const float* __restrict__ g2part,
                                                  const float* __restrict__ b2,
                                                  const int* __restrict__ lid,
                                                  float* __restrict__ pooledf) {
  int b = blockIdx.x; int tid = threadIdx.x;
  int lang = lid[b];
  int col = tid * 4;
  float4 acc = *(const float4*)(b2 + (size_t)lang * Hq + col);
#pragma unroll
  for (int ks = 0; ks < 4; ks++) {
    float4 p = *(const float4*)(g2part + ((size_t)(b * 4 + ks) * Hq) + col);
    acc.x += p.x; acc.y += p.y; acc.z += p.z; acc.w += p.w;
  }
  *(float4*)(pooledf + (size_t)b * Hq + col) = acc;
}

// ---------------------------------------------------------------- final matmul split-K partials
// grid = 32b x 9kslice (8x128 from pooledf + 1x100 from lda), 256 thr, float2 cols
__global__ __launch_bounds__(256) void k_fpart(const float* __restrict__ pooledf,
                                               const float* __restrict__ lda,
                                               const float* __restrict__ wf,
                                               float* __restrict__ fpart) {
  __shared__ float sc[128];
  int blk = blockIdx.x;
  int b = blk / 9, ks = blk % 9;
  int tid = threadIdx.x;
  int klen = (ks < 8) ? 128 : 100;
  int kbase = (ks < 8) ? ks * 128 : Hq;   // row offset into wf
  if (tid < klen) sc[tid] = (ks < 8) ? pooledf[b * Hq + kbase + tid] : lda[b * Tq + tid];
  __syncthreads();
  const float* W = wf + (size_t)kbase * Fq + tid * 2;
  float a0 = 0.f, a1 = 0.f;
  int k0 = 0;
  for (; k0 + 8 <= klen; k0 += 8) {
    float2 w[8];
#pragma unroll
    for (int j = 0; j < 8; j++) w[j] = *(const float2*)(W + (size_t)(k0 + j) * Fq);
#pragma unroll
    for (int j = 0; j < 8; j++) { float c = sc[k0 + j]; a0 += c * w[j].x; a1 += c * w[j].y; }
  }
  for (; k0 < klen; k0++) {
    float2 w = *(const float2*)(W + (size_t)k0 * Fq);
    float c = sc[k0];
    a0 += c * w.x; a1 += c * w.y;
  }
  float2* dst = (float2*)(fpart + (size_t)blk * Fq + tid * 2);
  *dst = make_float2(a0, a1);
}

// ---------------------------------------------------------------- reduce 9 slices + bf, LN, relu -> f32 out
__global__ __launch_bounds__(512) void k_final2(const float* __restrict__ fpart,
                                                const float* __restrict__ bff,
                                                const float* __restrict__ gf,
                                                const float* __restrict__ betaf,
                                                float* __restrict__ out) {
  __shared__ float rsum[8], rsq[8];
  int b = blockIdx.x; int tid = threadIdx.x;  // 512
  float acc = bff[tid];
#pragma unroll
  for (int ks = 0; ks < 9; ks++) acc += fpart[((size_t)b * 9 + ks) * Fq + tid];
  float s = acc, q = acc * acc;
#pragma unroll
  for (int off = 1; off < 64; off <<= 1) {
    s += __shfl_xor(s, off, 64);
    q += __shfl_xor(q, off, 64);
  }
  int w = tid >> 6, lane = tid & 63;
  if (lane == 0) { rsum[w] = s; rsq[w] = q; }
  __syncthreads();
  float S = 0.f, Q = 0.f;
#pragma unroll
  for (int i = 0; i < 8; i++) { S += rsum[i]; Q += rsq[i]; }
  float mu = S * (1.f / Fq);
  float var = Q * (1.f / Fq) - mu * mu;
  float y = (acc - mu) * rsqrtf(var + EPSq) * gf[tid] + betaf[tid];
  y = fmaxf(y, 0.f);
  out[b * Fq + tid] = y;   // f32 output
}

// ----------------------------------------------------------------
extern "C" void kernel_launch(void* const* d_in, const int* in_sizes, int n_in,
                              void* d_out, int out_size, void* d_ws, size_t ws_size,
                              hipStream_t stream) {
  const float* seq = (const float*)d_in[0];
  const float* mask = (const float*)d_in[1];
  const int* lid = (const int*)d_in[2];
  const float* lda = (const float*)d_in[3];
  const float* W1 = (const float*)d_in[4];
  const float* b1 = (const float*)d_in[5];
  const float* g1 = (const float*)d_in[6];
  const float* be1 = (const float*)d_in[7];
  const float* W2 = (const float*)d_in[8];
  const float* b2 = (const float*)d_in[9];
  const float* Wf = (const float*)d_in[10];
  const float* bff = (const float*)d_in[11];
  const float* gf = (const float*)d_in[12];
  const float* betaf = (const float*)d_in[13];
  float* out = (float*)d_out;

  // workspace layout
  char* ws = (char*)d_ws;
  unsigned short* seqbf = (unsigned short*)(ws);                  // 33,554,432 B
  unsigned short* w1t = (unsigned short*)(ws + 33554432);         // 10,485,760 B (consumed by gemm1)
  unsigned short* h1bf = (unsigned short*)(ws + 44040192);        // 33,554,432 B
  float* partial = (float*)(ws + 77594624);                       //  1,048,576 B
  float* pooled = (float*)(ws + 78643200);                        //    131,072 B
  float* pooledf = (float*)(ws + 78774272);                       //    131,072 B
  // reuse w1t region after gemm1 is done with it:
  float* g2part = (float*)(ws + 33554432);                        //    524,288 B
  float* fpart = (float*)(ws + 33554432 + 524288);                //    589,824 B

  k_convert_seq<<<8192, 256, 0, stream>>>(seq, seqbf);
  k_transpose_w1<<<5120, dim3(32, 8), 0, stream>>>(W1, w1t);
  k_gemm1<<<1024, 256, 0, stream>>>(seqbf, w1t, b1, lid, h1bf);
  k_ln_pool<<<256, 256, 0, stream>>>(h1bf, g1, be1, mask, lid, partial);
  k_reduce_pool<<<32, 256, 0, stream>>>(partial, mask, pooled);
  k_gemm2p<<<256, 256, 0, stream>>>(pooled, W2, lid, g2part);
  k_gemm2red<<<32, 256, 0, stream>>>(g2part, b2, lid, pooledf);
  k_fpart<<<288, 256, 0, stream>>>(pooledf, lda, Wf, fpart);
  k_final2<<<32, 512, 0, stream>>>(fpart, bff, gf, betaf, out);
}